// Round 8
// baseline (370.856 us; speedup 1.0000x reference)
//
#include <hip/hip_runtime.h>

#define NN 500000
#define FF 128
#define HH 128
#define BB 32768
#define KHOPS 4
#define EPER 524288              // RWS * B = 2^19
#define KE (KHOPS * EPER)        // 2097152
#define NOUT 8
#define SBLK 256                 // sort blocks
#define EPB (KE / SBLK)          // 8192 edges per sort block
#define GEMM_TILES 3907          // ceil(NN/128)

typedef unsigned short u16;
typedef unsigned char u8;
typedef __attribute__((ext_vector_type(8))) short short8v;   // 8 bf16 (4 VGPRs)
typedef __attribute__((ext_vector_type(4))) float f32x4;
typedef __attribute__((ext_vector_type(2))) float f32x2;

__device__ __forceinline__ float bflo(unsigned int u) {
    union { unsigned int x; float f; } t; t.x = u << 16; return t.f;
}
__device__ __forceinline__ float bfhi(unsigned int u) {
    union { unsigned int x; float f; } t; t.x = u & 0xFFFF0000u; return t.f;
}
__device__ __forceinline__ u16 f2bf(float f) {
    union { float f; unsigned int u; } t; t.f = f;
    unsigned int u = t.u;
    unsigned int r = (u + 0x7FFFu + ((u >> 16) & 1u)) >> 16;   // RNE
    return (u16)r;
}

// ---------- pre1: hist2(0..255) | degsum(256) | packW0(257) | dis(258..) ----------
__launch_bounds__(256, 2)
__global__ void k_pre1(const int* __restrict__ heads, u8* __restrict__ M,
                       const float* __restrict__ deg, const int* __restrict__ batch,
                       float* __restrict__ dsum, const float* __restrict__ W0,
                       u16* __restrict__ w0p, float* __restrict__ dis) {
    __shared__ unsigned int hp[8192];    // 32 KB (hist) / reused as reduce buf
    int tid = threadIdx.x;
    int bid = blockIdx.x;
    if (bid < SBLK) {
        // per-block histogram of heads into M[bid][BB] (u8, 4-packed)
        #pragma unroll
        for (int j = 0; j < 32; j++) hp[tid + j * 256] = 0;
        __syncthreads();
        int ebase = bid * EPB;
        #pragma unroll 4
        for (int it = 0; it < EPB / 256; it++) {
            int b = heads[ebase + it * 256 + tid];
            atomicAdd(&hp[b >> 2], 1u << ((b & 3) * 8));
        }
        __syncthreads();
        unsigned int* M32 = (unsigned int*)(M + (size_t)bid * BB);
        #pragma unroll
        for (int j = 0; j < 32; j++) {
            int w = tid + j * 256;
            M32[w] = hp[w];
        }
    } else if (bid == SBLK) {
        // deg-sum over batch (single block, 4 independent partials per thread)
        float* red = (float*)hp;
        float a0 = 0.f, a1 = 0.f, a2 = 0.f, a3 = 0.f;
        for (int i = tid; i < BB; i += 1024) {
            a0 += deg[batch[i]];
            a1 += deg[batch[i + 256]];
            a2 += deg[batch[i + 512]];
            a3 += deg[batch[i + 768]];
        }
        red[tid] = (a0 + a1) + (a2 + a3);
        __syncthreads();
        for (int off = 128; off > 0; off >>= 1) {
            if (tid < off) red[tid] += red[tid + off];
            __syncthreads();
        }
        if (tid == 0) dsum[0] = red[0];
    } else if (bid == SBLK + 1) {
        // pack W0 into MFMA B-fragment order, bf16
        for (int r = 0; r < 64; r++) {
            int f = r * 256 + tid;
            int k = f >> 7, c = f & 127;
            int kt = k >> 5, i = k & 7, lh = (k >> 3) & 3;
            int lane = lh * 16 + (c & 15), n = c >> 4;
            w0p[(((kt * 8 + n) * 64 + lane) << 3) + i] = f2bf(W0[f]);
        }
    } else {
        // dis[i] = rsqrt(deg[i])
        int i0 = (bid - SBLK - 2) * 1024 + tid * 4;
        if (i0 < NN) {                       // NN % 4 == 0
            float4 d = *(const float4*)&deg[i0];
            float4 o;
            o.x = rsqrtf(d.x); o.y = rsqrtf(d.y);
            o.z = rsqrtf(d.z); o.w = rsqrtf(d.w);
            *(float4*)&dis[i0] = o;
        }
    }
}

// ---------- pre2: colscan u32-packed (0..31) | disb (32..63) ----------
__global__ void k_pre2(u8* __restrict__ M, int* __restrict__ colsum,
                       const float* __restrict__ deg, const int* __restrict__ batch,
                       const float* __restrict__ dsum, float* __restrict__ disb) {
    int tid = threadIdx.x;
    if (blockIdx.x < 32) {
        // exclusive prefix down each key column, 4 keys/thread byte-parallel
        int g = blockIdx.x * 256 + tid;          // key-group (8192 total)
        unsigned int* M32 = (unsigned int*)M;
        unsigned int run = 0;
        #pragma unroll 8
        for (int b = 0; b < SBLK; b++) {
            size_t idx = (size_t)b * (BB / 4) + g;
            unsigned int v = M32[idx];
            M32[idx] = run;
            run += v;     // per-byte totals <= ~120, no cross-byte carry
        }
        colsum[g * 4 + 0] = (int)(run & 0xFFu);
        colsum[g * 4 + 1] = (int)((run >> 8) & 0xFFu);
        colsum[g * 4 + 2] = (int)((run >> 16) & 0xFFu);
        colsum[g * 4 + 3] = (int)((run >> 24) & 0xFFu);
    } else {
        // disb[b] = rsqrt(deg[batch[b]]) * dsum/EPER
        int b0 = (blockIdx.x - 32) * 1024 + tid * 4;
        float sc = dsum[0] * (1.0f / (float)EPER);
        #pragma unroll
        for (int t = 0; t < 4; t++) {
            int b = b0 + t;
            disb[b] = rsqrtf(deg[batch[b]]) * sc;
        }
    }
}

// ---------- scan of colsum -> base (single block, 1024 thr x 32) ----------
__global__ void k_scan(const int* __restrict__ colsum, int* __restrict__ base) {
    __shared__ int sc[1024];
    int tid = threadIdx.x;
    int loc[32];
    int run = 0;
    #pragma unroll
    for (int j = 0; j < 32; j++) {
        loc[j] = run;
        run += colsum[tid * 32 + j];
    }
    sc[tid] = run;
    __syncthreads();
    for (int off = 1; off < 1024; off <<= 1) {
        int v = (tid >= off) ? sc[tid - off] : 0;
        __syncthreads();
        sc[tid] += v;
        __syncthreads();
    }
    int excl = sc[tid] - run;
    #pragma unroll
    for (int j = 0; j < 32; j++) base[tid * 32 + j] = excl + loc[j];
    if (tid == 1023) base[BB] = sc[1023];     // = KE
}

// ---------- scatter (e, w) into pos = base[b] + M[blk][b] + local rank ----------
// Weight fully precomputed here so the gather inner loop is load+FMA only.
__launch_bounds__(256, 2)
__global__ void k_scatter2(const int* __restrict__ heads, const int* __restrict__ ends,
                           const u8* __restrict__ M, const int* __restrict__ base,
                           const float* __restrict__ dis, const float* __restrict__ disb,
                           const float* __restrict__ att, uint2* __restrict__ ewp) {
    __shared__ unsigned int hp[8192];
    int tid = threadIdx.x, blk = blockIdx.x;
    float attk = att[(blk >> 6) + 1];      // 64 sort blocks per hop
    #pragma unroll
    for (int j = 0; j < 32; j++) hp[tid + j * 256] = 0;
    __syncthreads();
    int ebase = blk * EPB;
    for (int it = 0; it < EPB / 256; it++) {
        int i = ebase + it * 256 + tid;
        int b = heads[i];
        int e = ends[i];
        float w = attk * disb[b] * dis[e];
        unsigned int old = atomicAdd(&hp[b >> 2], 1u << ((b & 3) * 8));
        unsigned int rank = (old >> ((b & 3) * 8)) & 0xFFu;
        int pos = base[b] + (int)M[(size_t)blk * BB + b] + (int)rank;
        uint2 pw;
        pw.x = (unsigned int)e;
        pw.y = __float_as_uint(w);
        ewp[pos] = pw;
    }
}

// ---------- GEMM1 (MFMA): h = bf16(relu(x @ W0 + b0)) over all N nodes ----------
// B-fragments read directly from global w0p (L2-hot 32 KB) — no ws LDS copy.
// LDS = 32 KB (A-tile, reused as epilogue store-staging) -> 4-5 blocks/CU.
__launch_bounds__(256, 5)
__global__ void k_gemm1(const float* __restrict__ x, const u16* __restrict__ w0p,
                        const float* __restrict__ b0, u16* __restrict__ h) {
    __shared__ u16 xs[128 * 128];     // 32 KB, XOR-swizzled bf16 A-tile
    int tid = threadIdx.x;
    int wid = tid >> 6;
    int lane = tid & 63;
    long rowbase = (long)blockIdx.x * 128;

    // stage x tile: fp32 -> bf16 -> swizzled LDS
    #pragma unroll
    for (int r = 0; r < 16; r++) {
        int f = tid + r * 256;            // 4096 float4
        int row = f >> 5;
        int c4 = (f & 31) * 4;
        long grow = rowbase + row; if (grow >= NN) grow = NN - 1;   // clamp tail
        float4 v = *(const float4*)&x[grow * 128 + c4];
        ushort4 pv;
        pv.x = f2bf(v.x); pv.y = f2bf(v.y); pv.z = f2bf(v.z); pv.w = f2bf(v.w);
        int byte = row * 256 + ((c4 * 2) ^ ((row & 7) << 4));
        *(ushort4*)((char*)xs + byte) = pv;
    }
    __syncthreads();

    short8v a[2][4];
    #pragma unroll
    for (int rs = 0; rs < 2; rs++) {
        int row = wid * 32 + rs * 16 + (lane & 15);
        int sw = (row & 7) << 4;
        #pragma unroll
        for (int kt = 0; kt < 4; kt++) {
            int kb = kt * 64 + (lane >> 4) * 16;
            a[rs][kt] = *(const short8v*)((const char*)xs + row * 256 + (kb ^ sw));
        }
    }

    f32x4 acc[2][8] = {};
    #pragma unroll
    for (int n = 0; n < 8; n++) {
        short8v bfr[4];
        #pragma unroll
        for (int kt = 0; kt < 4; kt++)
            bfr[kt] = *(const short8v*)&w0p[(((kt * 8 + n) * 64 + lane) << 3)];
        #pragma unroll
        for (int rs = 0; rs < 2; rs++) {
            #pragma unroll
            for (int kt = 0; kt < 4; kt++)
                acc[rs][n] = __builtin_amdgcn_mfma_f32_16x16x32_bf16(
                                 a[rs][kt], bfr[kt], acc[rs][n], 0, 0, 0);
        }
    }

    float b0v[8];
    #pragma unroll
    for (int n = 0; n < 8; n++) b0v[n] = b0[n * 16 + (lane & 15)];

    // stage relu(acc)+b0 into wave-private 8 KB stripe, then coalesced dwordx4
    u16* xw = &xs[wid * 32 * 128];
    #pragma unroll
    for (int rs = 0; rs < 2; rs++) {
        #pragma unroll
        for (int r = 0; r < 4; r++) {
            int row = rs * 16 + (lane >> 4) * 4 + r;      // 0..31 in stripe
            int sw = (row & 7) << 4;
            #pragma unroll
            for (int n = 0; n < 8; n++) {
                float v = acc[rs][n][r] + b0v[n];
                v = v > 0.f ? v : 0.f;
                int byte = row * 256 + ((n * 32 + (lane & 15) * 2) ^ sw);
                *(u16*)((char*)xw + byte) = f2bf(v);
            }
        }
    }
    __syncthreads();
    #pragma unroll
    for (int pass = 0; pass < 8; pass++) {
        int off = pass * 1024 + lane * 16;   // byte offset in stripe
        int row = off >> 8;                  // 0..31
        int colb = off & 255;
        int ocolb = colb ^ ((row & 7) << 4);
        long grow = rowbase + wid * 32 + row;
        uint4 v = *(const uint4*)((const char*)xw + off);
        if (grow < NN)
            *(uint4*)((char*)&h[grow * 128] + ocolb) = v;
    }
}

// ---------- gather: P[b,:] = att0*h[batch[b],:] + sum_j w_j * h[end_j,:] ----------
// 4 waves/block, wave owns row b. Quarter-wave q owns edge j+u*4+q; lane owns
// 8 cols. Inner loop is pure {b64 load, dwordx4 row, pk-FMA}.
__launch_bounds__(256)
__global__ void k_gather(const u16* __restrict__ h, const int* __restrict__ batch,
                         const int* __restrict__ base, const uint2* __restrict__ ewp,
                         const float* __restrict__ att,
                         float* __restrict__ P, float* __restrict__ s) {
    int b = blockIdx.x * 4 + (threadIdx.x >> 6);
    int l = threadIdx.x & 63;
    int q = l >> 4;
    int c8 = (l & 15) * 8;            // owns cols c8..c8+7
    float att0 = att[0];
    f32x2 acc2[4] = {{0.f, 0.f}, {0.f, 0.f}, {0.f, 0.f}, {0.f, 0.f}};
    float wsum = 0.f;

    if (q == 0) {
        int nb = batch[b];
        uint4 v = *(const uint4*)&h[(size_t)nb * 128 + c8];
        acc2[0] = f32x2{att0 * bflo(v.x), att0 * bfhi(v.x)};
        acc2[1] = f32x2{att0 * bflo(v.y), att0 * bfhi(v.y)};
        acc2[2] = f32x2{att0 * bflo(v.z), att0 * bfhi(v.z)};
        acc2[3] = f32x2{att0 * bflo(v.w), att0 * bfhi(v.w)};
    }

    int beg = base[b], fin = base[b + 1];
    for (int j = beg; j < fin; j += 32) {
        uint2 pw[8];
        #pragma unroll
        for (int u = 0; u < 8; u++) {
            int je = j + u * 4 + q;
            int jc = je < fin ? je : beg;     // always-valid index
            pw[u] = ewp[jc];
            if (je >= fin) pw[u].y = 0u;      // w = +0.0f
        }
        uint4 v[8];
        #pragma unroll
        for (int u = 0; u < 8; u++)
            v[u] = *(const uint4*)&h[(size_t)pw[u].x * 128 + c8];
        #pragma unroll
        for (int u = 0; u < 8; u++) {
            float w = __uint_as_float(pw[u].y);
            f32x2 w2 = {w, w};
            acc2[0] = __builtin_elementwise_fma(w2, f32x2{bflo(v[u].x), bfhi(v[u].x)}, acc2[0]);
            acc2[1] = __builtin_elementwise_fma(w2, f32x2{bflo(v[u].y), bfhi(v[u].y)}, acc2[1]);
            acc2[2] = __builtin_elementwise_fma(w2, f32x2{bflo(v[u].z), bfhi(v[u].z)}, acc2[2]);
            acc2[3] = __builtin_elementwise_fma(w2, f32x2{bflo(v[u].w), bfhi(v[u].w)}, acc2[3]);
            wsum += w;
        }
    }
    float accf[8] = { acc2[0].x, acc2[0].y, acc2[1].x, acc2[1].y,
                      acc2[2].x, acc2[2].y, acc2[3].x, acc2[3].y };
    #pragma unroll
    for (int k = 0; k < 8; k++) {
        accf[k] += __shfl_xor(accf[k], 16);
        accf[k] += __shfl_xor(accf[k], 32);
    }
    wsum += __shfl_xor(wsum, 16);
    wsum += __shfl_xor(wsum, 32);

    if (q == 0) {
        float4 o0 = { accf[0], accf[1], accf[2], accf[3] };
        float4 o1 = { accf[4], accf[5], accf[6], accf[7] };
        *(float4*)&P[(size_t)b * 128 + c8]     = o0;
        *(float4*)&P[(size_t)b * 128 + c8 + 4] = o1;
        if (l == 0) s[b] = att0 + wsum;
    }
}

// ---------- fused epilogue: aggx = P@W1 + s*b1; relu; @W2 + b2; log_softmax ----------
__launch_bounds__(256, 2)
__global__ void k_out(const float* __restrict__ P, const float* __restrict__ s,
                      const float* __restrict__ W1, const float* __restrict__ b1,
                      const float* __restrict__ W2, const float* __restrict__ b2,
                      float* __restrict__ out) {
    __shared__ float W1s[128 * 128];  // 64 KB
    __shared__ float Ps[32 * 128];    // 16 KB, reused as relu(aggx)
    int tid = threadIdx.x;
    int rowbase = blockIdx.x * 32;
    #pragma unroll
    for (int rep = 0; rep < 16; rep++) {
        int f = tid + rep * 256;
        *(float4*)&W1s[f * 4] = *(const float4*)&W1[f * 4];
    }
    #pragma unroll
    for (int rep = 0; rep < 4; rep++) {
        int f = tid + rep * 256;
        *(float4*)&Ps[f * 4] = *(const float4*)&P[(size_t)rowbase * 128 + f * 4];
    }
    __syncthreads();

    int c0 = (tid & 31) * 4;
    int r0 = (tid >> 5) * 4;
    float b1r[4] = { b1[c0], b1[c0 + 1], b1[c0 + 2], b1[c0 + 3] };
    float sv[4];
    #pragma unroll
    for (int j = 0; j < 4; j++) sv[j] = s[rowbase + r0 + j];

    float acc[4][4] = {};
    #pragma unroll 2
    for (int i = 0; i < 128; i += 4) {
        float4 xq[4], wq4[4];
        #pragma unroll
        for (int j = 0; j < 4; j++) xq[j]  = *(const float4*)&Ps[(r0 + j) * 128 + i];
        #pragma unroll
        for (int q = 0; q < 4; q++) wq4[q] = *(const float4*)&W1s[(i + q) * 128 + c0];
        #pragma unroll
        for (int j = 0; j < 4; j++) {
            float xv[4] = { xq[j].x, xq[j].y, xq[j].z, xq[j].w };
            #pragma unroll
            for (int q = 0; q < 4; q++) {
                acc[j][0] += xv[q] * wq4[q].x;
                acc[j][1] += xv[q] * wq4[q].y;
                acc[j][2] += xv[q] * wq4[q].z;
                acc[j][3] += xv[q] * wq4[q].w;
            }
        }
    }
    __syncthreads();                  // all reads of Ps done before overwrite
    #pragma unroll
    for (int j = 0; j < 4; j++) {
        #pragma unroll
        for (int c = 0; c < 4; c++) {
            float v = acc[j][c] + sv[j] * b1r[c];
            Ps[(r0 + j) * 128 + c0 + c] = v > 0.f ? v : 0.f;
        }
    }
    __syncthreads();

    int row = tid >> 3;
    int o = tid & 7;
    int rot = (row * 4) & 127;
    float v = b2[o];
    #pragma unroll 4
    for (int ii = 0; ii < 128; ii++) {
        int i = (ii + rot) & 127;
        v += Ps[row * 128 + i] * W2[i * 8 + o];
    }
    float m = v;
    for (int d = 1; d < 8; d <<= 1) m = fmaxf(m, __shfl_xor(m, d, 8));
    float ex = expf(v - m);
    float sum = ex;
    for (int d = 1; d < 8; d <<= 1) sum += __shfl_xor(sum, d, 8);
    out[(size_t)(rowbase + row) * 8 + o] = (v - m) - logf(sum);
}

extern "C" void kernel_launch(void* const* d_in, const int* in_sizes, int n_in,
                              void* d_out, int out_size, void* d_ws, size_t ws_size,
                              hipStream_t stream) {
    const float* x     = (const float*)d_in[0];
    const float* W0    = (const float*)d_in[1];
    const float* b0    = (const float*)d_in[2];
    const float* W1    = (const float*)d_in[3];
    const float* b1    = (const float*)d_in[4];
    const float* W2    = (const float*)d_in[5];
    const float* b2    = (const float*)d_in[6];
    const float* att   = (const float*)d_in[7];
    const float* deg   = (const float*)d_in[8];
    const int*   batch = (const int*)d_in[9];
    const int*   heads = (const int*)d_in[10];
    const int*   ends  = (const int*)d_in[11];
    float* out = (float*)d_out;

    char* w = (char*)d_ws;
    size_t off = 0;
    u16* h = (u16*)(w + off);          off += (size_t)NN * 128 * 2;       // 128 MB
    float* P = (float*)(w + off);      off += (size_t)BB * 128 * 4;       // 16 MB
    float* s = (float*)(w + off);      off += (size_t)BB * 4;
    int* base = (int*)(w + off);       off += 131328;                     // (B+1)*4 padded
    uint2* ewp = (uint2*)(w + off);    off += (size_t)KE * 8;             // (e, w)
    u8* M = (u8*)(w + off);            off += (size_t)SBLK * BB;          // 8 MB hist
    int* colsum = (int*)(w + off);     off += (size_t)BB * 4;
    float* dis = (float*)(w + off);    off += (size_t)NN * 4;             // rsqrt(deg)
    float* disb = (float*)(w + off);   off += (size_t)BB * 4;
    float* dsum = (float*)(w + off);   off += 256;
    u16* w0p = (u16*)(w + off);        off += 16384 * 2;                  // packed W0

    int disBlocks = (NN + 1023) / 1024;                 // 489
    k_pre1<<<SBLK + 2 + disBlocks, 256, 0, stream>>>(heads, M, deg, batch,
                                                     dsum, W0, w0p, dis);
    k_pre2<<<64, 256, 0, stream>>>(M, colsum, deg, batch, dsum, disb);
    k_scan<<<1, 1024, 0, stream>>>(colsum, base);
    k_scatter2<<<SBLK, 256, 0, stream>>>(heads, ends, M, base, dis, disb, att, ewp);
    k_gemm1<<<GEMM_TILES, 256, 0, stream>>>(x, w0p, b0, h);
    k_gather<<<BB / 4, 256, 0, stream>>>(h, batch, base, ewp, att, P, s);
    k_out<<<BB / 32, 256, 0, stream>>>(P, s, W1, b1, W2, b2, out);
}

// Round 9
// 360.339 us; speedup vs baseline: 1.0292x; 1.0292x over previous
//
#include <hip/hip_runtime.h>

#define NN 500000
#define FF 128
#define HH 128
#define BB 32768
#define KHOPS 4
#define EPER 524288              // RWS * B = 2^19
#define KE (KHOPS * EPER)        // 2097152
#define NOUT 8
#define SBLK 256                 // sort blocks
#define EPB (KE / SBLK)          // 8192 edges per sort block
#define GEMM_TILES ((NN + 63) / 64)   // 7813

typedef unsigned short u16;
typedef unsigned char u8;
typedef __attribute__((ext_vector_type(8))) short short8v;   // 8 bf16 (4 VGPRs)
typedef __attribute__((ext_vector_type(4))) float f32x4;

__device__ __forceinline__ float bflo(unsigned int u) {
    union { unsigned int x; float f; } t; t.x = u << 16; return t.f;
}
__device__ __forceinline__ float bfhi(unsigned int u) {
    union { unsigned int x; float f; } t; t.x = u & 0xFFFF0000u; return t.f;
}
__device__ __forceinline__ u16 f2bf(float f) {
    union { float f; unsigned int u; } t; t.f = f;
    unsigned int u = t.u;
    unsigned int r = (u + 0x7FFFu + ((u >> 16) & 1u)) >> 16;   // RNE
    return (u16)r;
}

// ---------- pre1: hist2(0..255) | degsum(256) | packW0(257) | dis(258..) ----------
__launch_bounds__(256, 2)
__global__ void k_pre1(const int* __restrict__ heads, u8* __restrict__ M,
                       const float* __restrict__ deg, const int* __restrict__ batch,
                       float* __restrict__ dsum, const float* __restrict__ W0,
                       u16* __restrict__ w0p, float* __restrict__ dis) {
    __shared__ unsigned int hp[8192];    // 32 KB (hist) / reused as reduce buf
    int tid = threadIdx.x;
    int bid = blockIdx.x;
    if (bid < SBLK) {
        // per-block histogram of heads into M[bid][BB] (u8, 4-packed)
        #pragma unroll
        for (int j = 0; j < 32; j++) hp[tid + j * 256] = 0;
        __syncthreads();
        int ebase = bid * EPB;
        #pragma unroll 4
        for (int it = 0; it < EPB / 256; it++) {
            int b = heads[ebase + it * 256 + tid];
            atomicAdd(&hp[b >> 2], 1u << ((b & 3) * 8));
        }
        __syncthreads();
        unsigned int* M32 = (unsigned int*)(M + (size_t)bid * BB);
        #pragma unroll
        for (int j = 0; j < 32; j++) {
            int w = tid + j * 256;
            M32[w] = hp[w];
        }
    } else if (bid == SBLK) {
        // deg-sum over batch (single block)
        float* red = (float*)hp;
        float a0 = 0.f, a1 = 0.f, a2 = 0.f, a3 = 0.f;
        for (int i = tid; i < BB; i += 1024) {
            a0 += deg[batch[i]];
            a1 += deg[batch[i + 256]];
            a2 += deg[batch[i + 512]];
            a3 += deg[batch[i + 768]];
        }
        red[tid] = (a0 + a1) + (a2 + a3);
        __syncthreads();
        for (int off = 128; off > 0; off >>= 1) {
            if (tid < off) red[tid] += red[tid + off];
            __syncthreads();
        }
        if (tid == 0) dsum[0] = red[0];
    } else if (bid == SBLK + 1) {
        // pack W0 into MFMA B-fragment order, bf16
        for (int r = 0; r < 64; r++) {
            int f = r * 256 + tid;
            int k = f >> 7, c = f & 127;
            int kt = k >> 5, i = k & 7, lh = (k >> 3) & 3;
            int lane = lh * 16 + (c & 15), n = c >> 4;
            w0p[(((kt * 8 + n) * 64 + lane) << 3) + i] = f2bf(W0[f]);
        }
    } else {
        // dis[i] = rsqrt(deg[i])
        int i0 = (bid - SBLK - 2) * 1024 + tid * 4;
        if (i0 < NN) {                       // NN % 4 == 0
            float4 d = *(const float4*)&deg[i0];
            float4 o;
            o.x = rsqrtf(d.x); o.y = rsqrtf(d.y);
            o.z = rsqrtf(d.z); o.w = rsqrtf(d.w);
            *(float4*)&dis[i0] = o;
        }
    }
}

// ---------- pre2: colscan u32-packed (0..31) | disb (32..63) ----------
__global__ void k_pre2(u8* __restrict__ M, int* __restrict__ colsum,
                       const float* __restrict__ deg, const int* __restrict__ batch,
                       const float* __restrict__ dsum, float* __restrict__ disb) {
    int tid = threadIdx.x;
    if (blockIdx.x < 32) {
        int g = blockIdx.x * 256 + tid;          // key-group (8192 total)
        unsigned int* M32 = (unsigned int*)M;
        unsigned int run = 0;
        #pragma unroll 8
        for (int b = 0; b < SBLK; b++) {
            size_t idx = (size_t)b * (BB / 4) + g;
            unsigned int v = M32[idx];
            M32[idx] = run;
            run += v;     // per-byte totals <= ~120, no cross-byte carry
        }
        colsum[g * 4 + 0] = (int)(run & 0xFFu);
        colsum[g * 4 + 1] = (int)((run >> 8) & 0xFFu);
        colsum[g * 4 + 2] = (int)((run >> 16) & 0xFFu);
        colsum[g * 4 + 3] = (int)((run >> 24) & 0xFFu);
    } else {
        int b0 = (blockIdx.x - 32) * 1024 + tid * 4;
        float sc = dsum[0] * (1.0f / (float)EPER);
        #pragma unroll
        for (int t = 0; t < 4; t++) {
            int b = b0 + t;
            disb[b] = rsqrtf(deg[batch[b]]) * sc;
        }
    }
}

// ---------- scan of colsum -> base (single block, 1024 thr x 32) ----------
__global__ void k_scan(const int* __restrict__ colsum, int* __restrict__ base) {
    __shared__ int sc[1024];
    int tid = threadIdx.x;
    int loc[32];
    int run = 0;
    #pragma unroll
    for (int j = 0; j < 32; j++) {
        loc[j] = run;
        run += colsum[tid * 32 + j];
    }
    sc[tid] = run;
    __syncthreads();
    for (int off = 1; off < 1024; off <<= 1) {
        int v = (tid >= off) ? sc[tid - off] : 0;
        __syncthreads();
        sc[tid] += v;
        __syncthreads();
    }
    int excl = sc[tid] - run;
    #pragma unroll
    for (int j = 0; j < 32; j++) base[tid * 32 + j] = excl + loc[j];
    if (tid == 1023) base[BB] = sc[1023];     // = KE
}

// ---------- scatter packed (hop<<19)|end into pos = base[b]+M[blk][b]+rank ----------
__launch_bounds__(256, 2)
__global__ void k_scatter2(const int* __restrict__ heads, const int* __restrict__ ends,
                           const u8* __restrict__ M, const int* __restrict__ base,
                           unsigned int* __restrict__ pe) {
    __shared__ unsigned int hp[8192];
    int tid = threadIdx.x, blk = blockIdx.x;
    #pragma unroll
    for (int j = 0; j < 32; j++) hp[tid + j * 256] = 0;
    __syncthreads();
    int ebase = blk * EPB;
    for (int it = 0; it < EPB / 256; it++) {
        int i = ebase + it * 256 + tid;
        int b = heads[i];
        unsigned int e = (unsigned int)ends[i];
        unsigned int kk = (unsigned int)(i >> 19);   // EPER = 2^19
        unsigned int old = atomicAdd(&hp[b >> 2], 1u << ((b & 3) * 8));
        unsigned int rank = (old >> ((b & 3) * 8)) & 0xFFu;
        int pos = base[b] + (int)M[(size_t)blk * BB + b] + (int)rank;
        pe[pos] = (kk << 19) | e;
    }
}

// ---------- GEMM1 (MFMA): h = bf16(relu(x @ W0 + b0)) over all N nodes ----------
// 64-row tiles, 16 KB LDS, B-fragments direct from L2-hot w0p. High occupancy
// (4 waves/SIMD by VGPR cap) to hide x-staging latency.
__launch_bounds__(256, 4)
__global__ void k_gemm1(const float* __restrict__ x, const u16* __restrict__ w0p,
                        const float* __restrict__ b0, u16* __restrict__ h) {
    __shared__ u16 xs[64 * 128];      // 16 KB, XOR-swizzled bf16 A-tile
    int tid = threadIdx.x;
    int wid = tid >> 6;
    int lane = tid & 63;
    long rowbase = (long)blockIdx.x * 64;

    // stage x tile: fp32 -> bf16 -> swizzled LDS (2048 float4, 8 per thread)
    #pragma unroll
    for (int r = 0; r < 8; r++) {
        int f = tid + r * 256;
        int row = f >> 5;
        int c4 = (f & 31) * 4;
        long grow = rowbase + row; if (grow >= NN) grow = NN - 1;   // clamp tail
        float4 v = *(const float4*)&x[grow * 128 + c4];
        ushort4 pv;
        pv.x = f2bf(v.x); pv.y = f2bf(v.y); pv.z = f2bf(v.z); pv.w = f2bf(v.w);
        int byte = row * 256 + ((c4 * 2) ^ ((row & 7) << 4));
        *(ushort4*)((char*)xs + byte) = pv;
    }
    __syncthreads();

    // A fragments: wave owns 16 rows
    short8v a[4];
    {
        int row = wid * 16 + (lane & 15);
        int sw = (row & 7) << 4;
        #pragma unroll
        for (int kt = 0; kt < 4; kt++) {
            int kb = kt * 64 + (lane >> 4) * 16;
            a[kt] = *(const short8v*)((const char*)xs + row * 256 + (kb ^ sw));
        }
    }

    f32x4 acc[8] = {};
    #pragma unroll
    for (int n = 0; n < 8; n++) {
        short8v bfr[4];
        #pragma unroll
        for (int kt = 0; kt < 4; kt++)
            bfr[kt] = *(const short8v*)&w0p[(((kt * 8 + n) * 64 + lane) << 3)];
        #pragma unroll
        for (int kt = 0; kt < 4; kt++)
            acc[n] = __builtin_amdgcn_mfma_f32_16x16x32_bf16(a[kt], bfr[kt],
                                                             acc[n], 0, 0, 0);
    }

    float b0v[8];
    #pragma unroll
    for (int n = 0; n < 8; n++) b0v[n] = b0[n * 16 + (lane & 15)];

    // stage relu(acc)+b0 into wave-private 4 KB stripe, then coalesced dwordx4
    __syncthreads();   // all A-fragment reads done before overwrite
    u16* xw = &xs[wid * 16 * 128];
    #pragma unroll
    for (int r = 0; r < 4; r++) {
        int row = (lane >> 4) * 4 + r;        // 0..15 in stripe
        int sw = (row & 7) << 4;
        #pragma unroll
        for (int n = 0; n < 8; n++) {
            float v = acc[n][r] + b0v[n];
            v = v > 0.f ? v : 0.f;
            int byte = row * 256 + ((n * 32 + (lane & 15) * 2) ^ sw);
            *(u16*)((char*)xw + byte) = f2bf(v);
        }
    }
    __syncthreads();
    #pragma unroll
    for (int pass = 0; pass < 4; pass++) {
        int off = pass * 1024 + lane * 16;   // byte offset in 4 KB stripe
        int row = off >> 8;                  // 0..15
        int colb = off & 255;
        int ocolb = colb ^ ((row & 7) << 4);
        long grow = rowbase + wid * 16 + row;
        uint4 v = *(const uint4*)((const char*)xw + off);
        if (grow < NN)
            *(uint4*)((char*)&h[grow * 128] + ocolb) = v;
    }
}

// ---------- gather: P[b,:] = att0*h[batch[b],:] + sum_j w_j * h[end_j,:] ----------
// 4 waves/block, wave owns row b. Quarter-wave q owns edge j+u*4+q; lane owns
// 8 cols. Unroll 8: 8 independent h-row loads in flight per wave. Weight
// recomputed from L2-hot dis[] + att cndmask select (4B/edge payload).
__launch_bounds__(256)
__global__ void k_gather(const u16* __restrict__ h, const int* __restrict__ batch,
                         const int* __restrict__ base, const unsigned int* __restrict__ pe,
                         const float* __restrict__ dis, const float* __restrict__ disb,
                         const float* __restrict__ att,
                         float* __restrict__ P, float* __restrict__ s) {
    int b = blockIdx.x * 4 + (threadIdx.x >> 6);
    int l = threadIdx.x & 63;
    int q = l >> 4;
    int c8 = (l & 15) * 8;            // owns cols c8..c8+7
    float att0 = att[0];
    float a1 = att[1], a2 = att[2], a3 = att[3], a4 = att[4];
    float dbv = disb[b];
    float acc[8] = {0.f, 0.f, 0.f, 0.f, 0.f, 0.f, 0.f, 0.f};

    if (q == 0) {
        int nb = batch[b];
        uint4 v = *(const uint4*)&h[(size_t)nb * 128 + c8];
        acc[0] = att0 * bflo(v.x); acc[1] = att0 * bfhi(v.x);
        acc[2] = att0 * bflo(v.y); acc[3] = att0 * bfhi(v.y);
        acc[4] = att0 * bflo(v.z); acc[5] = att0 * bfhi(v.z);
        acc[6] = att0 * bflo(v.w); acc[7] = att0 * bfhi(v.w);
    }

    int beg = base[b], fin = base[b + 1];
    float wsum = 0.f;
    for (int j = beg; j < fin; j += 32) {
        unsigned int p[8];
        #pragma unroll
        for (int u = 0; u < 8; u++) {
            int je = j + u * 4 + q;
            int jc = je < fin ? je : beg;     // always-valid index
            p[u] = pe[jc];
            if (je >= fin) p[u] |= 0x80000000u;   // mark dead
        }
        float wv[8];
        uint4 v[8];
        #pragma unroll
        for (int u = 0; u < 8; u++) {
            int e = (int)(p[u] & 0x7FFFFu);
            int kk = (int)((p[u] >> 19) & 3u);
            float av = (kk < 2) ? (kk == 0 ? a1 : a2) : (kk == 2 ? a3 : a4);
            float w = av * dbv * dis[e];
            wv[u] = (p[u] & 0x80000000u) ? 0.f : w;
            v[u] = *(const uint4*)&h[(size_t)e * 128 + c8];
        }
        #pragma unroll
        for (int u = 0; u < 8; u++) {
            float w = wv[u];
            acc[0] += w * bflo(v[u].x); acc[1] += w * bfhi(v[u].x);
            acc[2] += w * bflo(v[u].y); acc[3] += w * bfhi(v[u].y);
            acc[4] += w * bflo(v[u].z); acc[5] += w * bfhi(v[u].z);
            acc[6] += w * bflo(v[u].w); acc[7] += w * bfhi(v[u].w);
            wsum += w;
        }
    }
    #pragma unroll
    for (int k = 0; k < 8; k++) {
        acc[k] += __shfl_xor(acc[k], 16);
        acc[k] += __shfl_xor(acc[k], 32);
    }
    wsum += __shfl_xor(wsum, 16);
    wsum += __shfl_xor(wsum, 32);

    if (q == 0) {
        float4 o0 = { acc[0], acc[1], acc[2], acc[3] };
        float4 o1 = { acc[4], acc[5], acc[6], acc[7] };
        *(float4*)&P[(size_t)b * 128 + c8]     = o0;
        *(float4*)&P[(size_t)b * 128 + c8 + 4] = o1;
        if (l == 0) s[b] = att0 + wsum;
    }
}

// ---------- fused epilogue: aggx = P@W1 + s*b1; relu; @W2 + b2; log_softmax ----------
__launch_bounds__(256, 2)
__global__ void k_out(const float* __restrict__ P, const float* __restrict__ s,
                      const float* __restrict__ W1, const float* __restrict__ b1,
                      const float* __restrict__ W2, const float* __restrict__ b2,
                      float* __restrict__ out) {
    __shared__ float W1s[128 * 128];  // 64 KB
    __shared__ float Ps[32 * 128];    // 16 KB, reused as relu(aggx)
    int tid = threadIdx.x;
    int rowbase = blockIdx.x * 32;
    #pragma unroll
    for (int rep = 0; rep < 16; rep++) {
        int f = tid + rep * 256;
        *(float4*)&W1s[f * 4] = *(const float4*)&W1[f * 4];
    }
    #pragma unroll
    for (int rep = 0; rep < 4; rep++) {
        int f = tid + rep * 256;
        *(float4*)&Ps[f * 4] = *(const float4*)&P[(size_t)rowbase * 128 + f * 4];
    }
    __syncthreads();

    int c0 = (tid & 31) * 4;
    int r0 = (tid >> 5) * 4;
    float b1r[4] = { b1[c0], b1[c0 + 1], b1[c0 + 2], b1[c0 + 3] };
    float sv[4];
    #pragma unroll
    for (int j = 0; j < 4; j++) sv[j] = s[rowbase + r0 + j];

    float acc[4][4] = {};
    #pragma unroll 2
    for (int i = 0; i < 128; i += 4) {
        float4 xq[4], wq4[4];
        #pragma unroll
        for (int j = 0; j < 4; j++) xq[j]  = *(const float4*)&Ps[(r0 + j) * 128 + i];
        #pragma unroll
        for (int q = 0; q < 4; q++) wq4[q] = *(const float4*)&W1s[(i + q) * 128 + c0];
        #pragma unroll
        for (int j = 0; j < 4; j++) {
            float xv[4] = { xq[j].x, xq[j].y, xq[j].z, xq[j].w };
            #pragma unroll
            for (int q = 0; q < 4; q++) {
                acc[j][0] += xv[q] * wq4[q].x;
                acc[j][1] += xv[q] * wq4[q].y;
                acc[j][2] += xv[q] * wq4[q].z;
                acc[j][3] += xv[q] * wq4[q].w;
            }
        }
    }
    __syncthreads();                  // all reads of Ps done before overwrite
    #pragma unroll
    for (int j = 0; j < 4; j++) {
        #pragma unroll
        for (int c = 0; c < 4; c++) {
            float v = acc[j][c] + sv[j] * b1r[c];
            Ps[(r0 + j) * 128 + c0 + c] = v > 0.f ? v : 0.f;
        }
    }
    __syncthreads();

    int row = tid >> 3;
    int o = tid & 7;
    int rot = (row * 4) & 127;
    float v = b2[o];
    #pragma unroll 4
    for (int ii = 0; ii < 128; ii++) {
        int i = (ii + rot) & 127;
        v += Ps[row * 128 + i] * W2[i * 8 + o];
    }
    float m = v;
    for (int d = 1; d < 8; d <<= 1) m = fmaxf(m, __shfl_xor(m, d, 8));
    float ex = expf(v - m);
    float sum = ex;
    for (int d = 1; d < 8; d <<= 1) sum += __shfl_xor(sum, d, 8);
    out[(size_t)(rowbase + row) * 8 + o] = (v - m) - logf(sum);
}

extern "C" void kernel_launch(void* const* d_in, const int* in_sizes, int n_in,
                              void* d_out, int out_size, void* d_ws, size_t ws_size,
                              hipStream_t stream) {
    const float* x     = (const float*)d_in[0];
    const float* W0    = (const float*)d_in[1];
    const float* b0    = (const float*)d_in[2];
    const float* W1    = (const float*)d_in[3];
    const float* b1    = (const float*)d_in[4];
    const float* W2    = (const float*)d_in[5];
    const float* b2    = (const float*)d_in[6];
    const float* att   = (const float*)d_in[7];
    const float* deg   = (const float*)d_in[8];
    const int*   batch = (const int*)d_in[9];
    const int*   heads = (const int*)d_in[10];
    const int*   ends  = (const int*)d_in[11];
    float* out = (float*)d_out;

    char* w = (char*)d_ws;
    size_t off = 0;
    u16* h = (u16*)(w + off);          off += (size_t)NN * 128 * 2;       // 128 MB
    float* P = (float*)(w + off);      off += (size_t)BB * 128 * 4;       // 16 MB
    float* s = (float*)(w + off);      off += (size_t)BB * 4;
    int* base = (int*)(w + off);       off += 131328;                     // (B+1)*4 padded
    unsigned int* pe = (unsigned int*)(w + off); off += (size_t)KE * 4;   // packed (k,e)
    u8* M = (u8*)(w + off);            off += (size_t)SBLK * BB;          // 8 MB hist
    int* colsum = (int*)(w + off);     off += (size_t)BB * 4;
    float* dis = (float*)(w + off);    off += (size_t)NN * 4;             // rsqrt(deg)
    float* disb = (float*)(w + off);   off += (size_t)BB * 4;
    float* dsum = (float*)(w + off);   off += 256;
    u16* w0p = (u16*)(w + off);        off += 16384 * 2;                  // packed W0

    int disBlocks = (NN + 1023) / 1024;                 // 489
    k_pre1<<<SBLK + 2 + disBlocks, 256, 0, stream>>>(heads, M, deg, batch,
                                                     dsum, W0, w0p, dis);
    k_pre2<<<64, 256, 0, stream>>>(M, colsum, deg, batch, dsum, disb);
    k_scan<<<1, 1024, 0, stream>>>(colsum, base);
    k_scatter2<<<SBLK, 256, 0, stream>>>(heads, ends, M, base, pe);
    k_gemm1<<<GEMM_TILES, 256, 0, stream>>>(x, w0p, b0, h);
    k_gather<<<BB / 4, 256, 0, stream>>>(h, batch, base, pe, dis, disb, att, P, s);
    k_out<<<BB / 32, 256, 0, stream>>>(P, s, W1, b1, W2, b2, out);
}

// Round 10
// 307.643 us; speedup vs baseline: 1.2055x; 1.1713x over previous
//
#include <hip/hip_runtime.h>

#define NN 500000
#define FF 128
#define HH 128
#define BB 32768
#define KHOPS 4
#define EPER 524288              // RWS * B = 2^19
#define KE (KHOPS * EPER)        // 2097152
#define NOUT 8
#define SBLK 256                 // sort blocks
#define EPB (KE / SBLK)          // 8192 edges per sort block

typedef unsigned short u16;
typedef unsigned char u8;
typedef __attribute__((ext_vector_type(8))) short short8v;   // 8 bf16 (4 VGPRs)
typedef __attribute__((ext_vector_type(4))) float f32x4;

__device__ __forceinline__ float bflo(unsigned int u) {
    union { unsigned int x; float f; } t; t.x = u << 16; return t.f;
}
__device__ __forceinline__ float bfhi(unsigned int u) {
    union { unsigned int x; float f; } t; t.x = u & 0xFFFF0000u; return t.f;
}
__device__ __forceinline__ u16 f2bf(float f) {
    union { float f; unsigned int u; } t; t.f = f;
    unsigned int u = t.u;
    unsigned int r = (u + 0x7FFFu + ((u >> 16) & 1u)) >> 16;   // RNE
    return (u16)r;
}

// ---------- deg-sum (two-stage, deterministic) ----------
__global__ void k_degsum1(const float* __restrict__ deg, const int* __restrict__ batch,
                          float* __restrict__ partial) {
    __shared__ float red[256];
    int i = blockIdx.x * 256 + threadIdx.x;       // exactly B = 128*256
    red[threadIdx.x] = deg[batch[i]];
    __syncthreads();
    for (int off = 128; off > 0; off >>= 1) {
        if (threadIdx.x < off) red[threadIdx.x] += red[threadIdx.x + off];
        __syncthreads();
    }
    if (threadIdx.x == 0) partial[blockIdx.x] = red[0];
}
__global__ void k_degsum2(const float* __restrict__ partial, float* __restrict__ dsum) {
    __shared__ float red[128];
    red[threadIdx.x] = partial[threadIdx.x];
    __syncthreads();
    for (int off = 64; off > 0; off >>= 1) {
        if (threadIdx.x < off) red[threadIdx.x] += red[threadIdx.x + off];
        __syncthreads();
    }
    if (threadIdx.x == 0) *dsum = red[0];
}

// ---------- precompute dis[e]=rsqrt(deg[e]), disb[b]=rsqrt(deg[batch[b]])*scale ----
__global__ void k_prep(const float* __restrict__ deg, const int* __restrict__ batch,
                       const float* __restrict__ dsum,
                       float* __restrict__ dis, float* __restrict__ disb) {
    int i = blockIdx.x * 256 + threadIdx.x;
    if (i < NN) dis[i] = rsqrtf(deg[i]);
    if (i < BB) disb[i] = rsqrtf(deg[batch[i]]) * (dsum[0] * (1.0f / (float)EPER));
}

// ---------- counting-sort CSR build (LDS atomics only, u8 counts) ----------
__launch_bounds__(256, 2)
__global__ void k_hist2(const int* __restrict__ heads, u8* __restrict__ M) {
    __shared__ unsigned int hp[8192];    // 32768 u8 counts, 32 KB
    int tid = threadIdx.x, blk = blockIdx.x;
    #pragma unroll
    for (int j = 0; j < 32; j++) hp[tid + j * 256] = 0;
    __syncthreads();
    int ebase = blk * EPB;
    #pragma unroll 4
    for (int it = 0; it < EPB / 256; it++) {
        int b = heads[ebase + it * 256 + tid];
        atomicAdd(&hp[b >> 2], 1u << ((b & 3) * 8));
    }
    __syncthreads();
    unsigned int* M32 = (unsigned int*)(M + (size_t)blk * BB);
    #pragma unroll
    for (int j = 0; j < 32; j++) {
        int w = tid + j * 256;
        M32[w] = hp[w];
    }
}

__global__ void k_colscan(u8* __restrict__ M, int* __restrict__ colsum) {
    int key = blockIdx.x * 256 + threadIdx.x;   // 128 blocks x 256
    unsigned int run = 0;
    #pragma unroll 8
    for (int b = 0; b < SBLK; b++) {
        size_t idx = (size_t)b * BB + key;
        u8 v = M[idx];
        M[idx] = (u8)run;               // per-key totals ~64 << 255
        run += v;
    }
    colsum[key] = (int)run;
}

__global__ void k_scan(const int* __restrict__ colsum, int* __restrict__ base) {
    __shared__ int sc[1024];
    int tid = threadIdx.x;
    int loc[32];
    int run = 0;
    #pragma unroll
    for (int j = 0; j < 32; j++) {
        loc[j] = run;
        run += colsum[tid * 32 + j];
    }
    sc[tid] = run;
    __syncthreads();
    for (int off = 1; off < 1024; off <<= 1) {
        int v = (tid >= off) ? sc[tid - off] : 0;
        __syncthreads();
        sc[tid] += v;
        __syncthreads();
    }
    int excl = sc[tid] - run;
    #pragma unroll
    for (int j = 0; j < 32; j++) base[tid * 32 + j] = excl + loc[j];
    if (tid == 1023) base[BB] = sc[1023];     // = KE
}

__launch_bounds__(256, 2)
__global__ void k_scatter2(const int* __restrict__ heads, const int* __restrict__ ends,
                           const u8* __restrict__ M, const int* __restrict__ base,
                           unsigned int* __restrict__ pe) {
    __shared__ unsigned int hp[8192];
    int tid = threadIdx.x, blk = blockIdx.x;
    #pragma unroll
    for (int j = 0; j < 32; j++) hp[tid + j * 256] = 0;
    __syncthreads();
    int ebase = blk * EPB;
    for (int it = 0; it < EPB / 256; it++) {
        int i = ebase + it * 256 + tid;
        int b = heads[i];
        unsigned int e = (unsigned int)ends[i];
        unsigned int kk = (unsigned int)(i >> 19);   // EPER = 2^19
        unsigned int old = atomicAdd(&hp[b >> 2], 1u << ((b & 3) * 8));
        unsigned int rank = (old >> ((b & 3) * 8)) & 0xFFu;
        int pos = base[b] + (int)M[(size_t)blk * BB + b] + (int)rank;
        pe[pos] = (kk << 19) | e;
    }
}

// ---------- pack W0 (fp32 [128][128]) into MFMA B-fragment order, bf16 ----------
__global__ void k_packW0(const float* __restrict__ W0, u16* __restrict__ w0p) {
    int f = blockIdx.x * 256 + threadIdx.x;   // 16384 total
    int k = f >> 7, c = f & 127;
    int kt = k >> 5, i = k & 7, lh = (k >> 3) & 3;
    int lane = lh * 16 + (c & 15), n = c >> 4;
    w0p[(((kt * 8 + n) * 64 + lane) << 3) + i] = f2bf(W0[f]);
}

// ---------- GEMM1 (MFMA): h = bf16(relu(x @ W0 + b0)) over all N nodes ----------
// A-fragments loaded DIRECTLY from global x (16 full cache lines per wave-load,
// no LDS, no barrier). LDS = 32 KB ws only (B fragments; reused post-barrier as
// the coalesced-store stage) -> 2x+ the resident blocks of the 64 KB version.
__launch_bounds__(256, 2)
__global__ void k_gemm1(const float* __restrict__ x, const u16* __restrict__ w0p,
                        const float* __restrict__ b0, u16* __restrict__ h) {
    __shared__ u16 ws[16384];         // 32 KB: packed B; later store-staging
    int tid = threadIdx.x;
    int wid = tid >> 6;
    int lane = tid & 63;
    long rowbase = (long)blockIdx.x * 128;

    // stage packed W0 (coalesced 16B, L2-hot)
    #pragma unroll
    for (int r = 0; r < 8; r++) {
        int f = tid + r * 256;        // 2048 x 16B
        *(float4*)&ws[f * 8] = *(const float4*)&w0p[f * 8];
    }

    // A fragments direct from global: row = wid*32+rs*16+(lane&15),
    // cols kt*32+(lane>>4)*8 .. +8  (two dwordx4 per fragment)
    short8v a[2][4];
    int qc = (lane >> 4) * 8;
    #pragma unroll
    for (int rs = 0; rs < 2; rs++) {
        long grow = rowbase + wid * 32 + rs * 16 + (lane & 15);
        if (grow >= NN) grow = NN - 1;            // clamp tail (rows 499968+)
        const float* xr = &x[grow * 128 + qc];
        #pragma unroll
        for (int kt = 0; kt < 4; kt++) {
            float4 v0 = *(const float4*)&xr[kt * 32];
            float4 v1 = *(const float4*)&xr[kt * 32 + 4];
            short8v f;
            f[0] = (short)f2bf(v0.x); f[1] = (short)f2bf(v0.y);
            f[2] = (short)f2bf(v0.z); f[3] = (short)f2bf(v0.w);
            f[4] = (short)f2bf(v1.x); f[5] = (short)f2bf(v1.y);
            f[6] = (short)f2bf(v1.z); f[7] = (short)f2bf(v1.w);
            a[rs][kt] = f;
        }
    }
    __syncthreads();                  // ws ready

    f32x4 acc[2][8] = {};
    #pragma unroll
    for (int n = 0; n < 8; n++) {
        short8v bfr[4];
        #pragma unroll
        for (int kt = 0; kt < 4; kt++)
            bfr[kt] = *(const short8v*)&ws[(((kt * 8 + n) * 64 + lane) << 3)];
        #pragma unroll
        for (int rs = 0; rs < 2; rs++) {
            #pragma unroll
            for (int kt = 0; kt < 4; kt++)
                acc[rs][n] = __builtin_amdgcn_mfma_f32_16x16x32_bf16(
                                 a[rs][kt], bfr[kt], acc[rs][n], 0, 0, 0);
        }
    }

    float b0v[8];
    #pragma unroll
    for (int n = 0; n < 8; n++) b0v[n] = b0[n * 16 + (lane & 15)];

    // reuse ws as wave-private 8 KB store-stage (XOR-swizzled), then dwordx4
    __syncthreads();                  // all B-fragment reads done
    u16* xw = &ws[wid * 32 * 128];
    #pragma unroll
    for (int rs = 0; rs < 2; rs++) {
        #pragma unroll
        for (int r = 0; r < 4; r++) {
            int row = rs * 16 + (lane >> 4) * 4 + r;      // 0..31 in stripe
            int sw = (row & 7) << 4;
            #pragma unroll
            for (int n = 0; n < 8; n++) {
                float v = acc[rs][n][r] + b0v[n];
                v = v > 0.f ? v : 0.f;
                int byte = row * 256 + ((n * 32 + (lane & 15) * 2) ^ sw);
                *(u16*)((char*)xw + byte) = f2bf(v);
            }
        }
    }
    __syncthreads();
    #pragma unroll
    for (int pass = 0; pass < 8; pass++) {
        int off = pass * 1024 + lane * 16;   // byte offset in stripe
        int row = off >> 8;                  // 0..31
        int colb = off & 255;
        int ocolb = colb ^ ((row & 7) << 4);
        long grow = rowbase + wid * 32 + row;
        uint4 v = *(const uint4*)((const char*)xw + off);
        if (grow < NN)
            *(uint4*)((char*)&h[grow * 128] + ocolb) = v;
    }
}

// ---------- gather: P[b,:] = att0*h[batch[b],:] + sum_j w_j * h[end_j,:] ----------
__launch_bounds__(256)
__global__ void k_gather(const u16* __restrict__ h, const int* __restrict__ batch,
                         const int* __restrict__ base, const unsigned int* __restrict__ pe,
                         const float* __restrict__ dis, const float* __restrict__ disb,
                         const float* __restrict__ att,
                         float* __restrict__ P, float* __restrict__ s) {
    int b = blockIdx.x * 4 + (threadIdx.x >> 6);
    int l = threadIdx.x & 63;
    int q = l >> 4;
    int c8 = (l & 15) * 8;            // owns cols c8..c8+7
    float att0 = att[0];
    float a1 = att[1], a2 = att[2], a3 = att[3], a4 = att[4];
    float dbv = disb[b];
    float acc[8] = {0.f, 0.f, 0.f, 0.f, 0.f, 0.f, 0.f, 0.f};

    if (q == 0) {
        int nb = batch[b];
        uint4 v = *(const uint4*)&h[(size_t)nb * 128 + c8];
        acc[0] = att0 * bflo(v.x); acc[1] = att0 * bfhi(v.x);
        acc[2] = att0 * bflo(v.y); acc[3] = att0 * bfhi(v.y);
        acc[4] = att0 * bflo(v.z); acc[5] = att0 * bfhi(v.z);
        acc[6] = att0 * bflo(v.w); acc[7] = att0 * bfhi(v.w);
    }

    int beg = base[b], fin = base[b + 1];
    float wsum = 0.f;
    for (int j = beg; j < fin; j += 32) {
        unsigned int p[8];
        #pragma unroll
        for (int u = 0; u < 8; u++) {
            int je = j + u * 4 + q;
            int jc = je < fin ? je : beg;     // always-valid index
            p[u] = pe[jc];
            if (je >= fin) p[u] |= 0x80000000u;   // mark dead
        }
        float wv[8];
        uint4 v[8];
        #pragma unroll
        for (int u = 0; u < 8; u++) {
            int e = (int)(p[u] & 0x7FFFFu);
            int kk = (int)((p[u] >> 19) & 3u);
            float av = (kk < 2) ? (kk == 0 ? a1 : a2) : (kk == 2 ? a3 : a4);
            float w = av * dbv * dis[e];
            wv[u] = (p[u] & 0x80000000u) ? 0.f : w;
            v[u] = *(const uint4*)&h[(size_t)e * 128 + c8];
        }
        #pragma unroll
        for (int u = 0; u < 8; u++) {
            float w = wv[u];
            acc[0] += w * bflo(v[u].x); acc[1] += w * bfhi(v[u].x);
            acc[2] += w * bflo(v[u].y); acc[3] += w * bfhi(v[u].y);
            acc[4] += w * bflo(v[u].z); acc[5] += w * bfhi(v[u].z);
            acc[6] += w * bflo(v[u].w); acc[7] += w * bfhi(v[u].w);
            wsum += w;
        }
    }
    #pragma unroll
    for (int k = 0; k < 8; k++) {
        acc[k] += __shfl_xor(acc[k], 16);
        acc[k] += __shfl_xor(acc[k], 32);
    }
    wsum += __shfl_xor(wsum, 16);
    wsum += __shfl_xor(wsum, 32);

    if (q == 0) {
        float4 o0 = { acc[0], acc[1], acc[2], acc[3] };
        float4 o1 = { acc[4], acc[5], acc[6], acc[7] };
        *(float4*)&P[(size_t)b * 128 + c8]     = o0;
        *(float4*)&P[(size_t)b * 128 + c8 + 4] = o1;
        if (l == 0) s[b] = att0 + wsum;
    }
}

// ---------- fused epilogue: aggx = P@W1 + s*b1; relu; @W2 + b2; log_softmax ----------
__launch_bounds__(256, 2)
__global__ void k_out(const float* __restrict__ P, const float* __restrict__ s,
                      const float* __restrict__ W1, const float* __restrict__ b1,
                      const float* __restrict__ W2, const float* __restrict__ b2,
                      float* __restrict__ out) {
    __shared__ float W1s[128 * 128];  // 64 KB
    __shared__ float Ps[32 * 128];    // 16 KB, reused as relu(aggx)
    int tid = threadIdx.x;
    int rowbase = blockIdx.x * 32;
    #pragma unroll
    for (int rep = 0; rep < 16; rep++) {
        int f = tid + rep * 256;
        *(float4*)&W1s[f * 4] = *(const float4*)&W1[f * 4];
    }
    #pragma unroll
    for (int rep = 0; rep < 4; rep++) {
        int f = tid + rep * 256;
        *(float4*)&Ps[f * 4] = *(const float4*)&P[(size_t)rowbase * 128 + f * 4];
    }
    __syncthreads();

    int c0 = (tid & 31) * 4;
    int r0 = (tid >> 5) * 4;
    float b1r[4] = { b1[c0], b1[c0 + 1], b1[c0 + 2], b1[c0 + 3] };
    float sv[4];
    #pragma unroll
    for (int j = 0; j < 4; j++) sv[j] = s[rowbase + r0 + j];

    float acc[4][4] = {};
    #pragma unroll 2
    for (int i = 0; i < 128; i += 4) {
        float4 xq[4], wq4[4];
        #pragma unroll
        for (int j = 0; j < 4; j++) xq[j]  = *(const float4*)&Ps[(r0 + j) * 128 + i];
        #pragma unroll
        for (int q = 0; q < 4; q++) wq4[q] = *(const float4*)&W1s[(i + q) * 128 + c0];
        #pragma unroll
        for (int j = 0; j < 4; j++) {
            float xv[4] = { xq[j].x, xq[j].y, xq[j].z, xq[j].w };
            #pragma unroll
            for (int q = 0; q < 4; q++) {
                acc[j][0] += xv[q] * wq4[q].x;
                acc[j][1] += xv[q] * wq4[q].y;
                acc[j][2] += xv[q] * wq4[q].z;
                acc[j][3] += xv[q] * wq4[q].w;
            }
        }
    }
    __syncthreads();                  // all reads of Ps done before overwrite
    #pragma unroll
    for (int j = 0; j < 4; j++) {
        #pragma unroll
        for (int c = 0; c < 4; c++) {
            float v = acc[j][c] + sv[j] * b1r[c];
            Ps[(r0 + j) * 128 + c0 + c] = v > 0.f ? v : 0.f;
        }
    }
    __syncthreads();

    int row = tid >> 3;
    int o = tid & 7;
    int rot = (row * 4) & 127;
    float v = b2[o];
    #pragma unroll 4
    for (int ii = 0; ii < 128; ii++) {
        int i = (ii + rot) & 127;
        v += Ps[row * 128 + i] * W2[i * 8 + o];
    }
    float m = v;
    for (int d = 1; d < 8; d <<= 1) m = fmaxf(m, __shfl_xor(m, d, 8));
    float ex = expf(v - m);
    float sum = ex;
    for (int d = 1; d < 8; d <<= 1) sum += __shfl_xor(sum, d, 8);
    out[(size_t)(rowbase + row) * 8 + o] = (v - m) - logf(sum);
}

extern "C" void kernel_launch(void* const* d_in, const int* in_sizes, int n_in,
                              void* d_out, int out_size, void* d_ws, size_t ws_size,
                              hipStream_t stream) {
    const float* x     = (const float*)d_in[0];
    const float* W0    = (const float*)d_in[1];
    const float* b0    = (const float*)d_in[2];
    const float* W1    = (const float*)d_in[3];
    const float* b1    = (const float*)d_in[4];
    const float* W2    = (const float*)d_in[5];
    const float* b2    = (const float*)d_in[6];
    const float* att   = (const float*)d_in[7];
    const float* deg   = (const float*)d_in[8];
    const int*   batch = (const int*)d_in[9];
    const int*   heads = (const int*)d_in[10];
    const int*   ends  = (const int*)d_in[11];
    float* out = (float*)d_out;

    char* w = (char*)d_ws;
    size_t off = 0;
    u16* h = (u16*)(w + off);          off += (size_t)NN * 128 * 2;       // 128 MB
    float* P = (float*)(w + off);      off += (size_t)BB * 128 * 4;       // 16 MB
    float* s = (float*)(w + off);      off += (size_t)BB * 4;
    int* base = (int*)(w + off);       off += 131328;                     // (B+1)*4 padded
    unsigned int* pe = (unsigned int*)(w + off); off += (size_t)KE * 4;   // packed (k,e)
    u8* M = (u8*)(w + off);            off += (size_t)SBLK * BB;          // 8 MB hist
    int* colsum = (int*)(w + off);     off += (size_t)BB * 4;
    float* dis = (float*)(w + off);    off += (size_t)NN * 4;             // rsqrt(deg)
    float* disb = (float*)(w + off);   off += (size_t)BB * 4;
    float* partial = (float*)(w + off); off += 1024;
    float* dsum = (float*)(w + off);   off += 256;
    u16* w0p = (u16*)(w + off);        off += 16384 * 2;                  // packed W0

    k_degsum1<<<128, 256, 0, stream>>>(deg, batch, partial);
    k_degsum2<<<1, 128, 0, stream>>>(partial, dsum);
    k_prep<<<(NN + 255) / 256, 256, 0, stream>>>(deg, batch, dsum, dis, disb);
    k_hist2<<<SBLK, 256, 0, stream>>>(heads, M);
    k_colscan<<<BB / 256, 256, 0, stream>>>(M, colsum);
    k_scan<<<1, 1024, 0, stream>>>(colsum, base);
    k_scatter2<<<SBLK, 256, 0, stream>>>(heads, ends, M, base, pe);
    k_packW0<<<64, 256, 0, stream>>>(W0, w0p);
    k_gemm1<<<(NN + 127) / 128, 256, 0, stream>>>(x, w0p, b0, h);
    k_gather<<<BB / 4, 256, 0, stream>>>(h, batch, base, pe, dis, disb, att, P, s);
    k_out<<<BB / 32, 256, 0, stream>>>(P, s, W1, b1, W2, b2, out);
}